// Round 10
// baseline (882.541 us; speedup 1.0000x reference)
//
#include <hip/hip_runtime.h>
#include <hip/hip_bf16.h>
#include <cstdint>
#include <cstddef>

typedef __bf16 bf16;
typedef __bf16 bf16x8 __attribute__((ext_vector_type(8)));
typedef float f32x4 __attribute__((ext_vector_type(4)));

#define N_PTS 131072
#define CDIM  512
#define C3    1536
#define HD    64
#define NH    8
#define KWIN  128
#define NKS   16          // CDIM/32 k-steps

static __device__ __forceinline__ bf16 cvt(float x) { return (bf16)x; }

// async global->LDS, 16B per lane (proj path only).
static __device__ __forceinline__ void gld16(const bf16* g, bf16* l) {
    __builtin_amdgcn_global_load_lds(
        (const __attribute__((address_space(1))) void*)g,
        (__attribute__((address_space(3))) void*)l, 16, 0, 0);
}

// ---------------------------------------------------------------------------
// Fragment-native chunk layout: chunk (rowfrag rf, kstep ks) is 1024B at
// element (rf*16+ks)*512; lane l's 16B at +l*8 holds
// (row = rf*16 + (l&15), k = ks*32 + (l>>4)*8 + e), e=0..7 — exactly the
// bf16x8 an MFMA A/B fragment wants. A frag load = 1 coalesced 1KB read.
// ---------------------------------------------------------------------------

// k_prep: Wqkv -> fragment-native (for the no-LDS qkv GEMM);
//         Wproj -> [col][k] transposed (for the R5 LDS proj GEMM).
__global__ __launch_bounds__(256) void k_prep(
    const float* __restrict__ Wqkv, const float* __restrict__ Wproj,
    bf16* __restrict__ Wq_frag, bf16* __restrict__ Wp_t)
{
    const int b = blockIdx.x, t = threadIdx.x;
    if (b < 384) {
        int slot  = b * 256 + t;       // 0..98303
        int chunk = slot >> 6;         // cf*16 + ks, 0..1535
        int l     = slot & 63;
        int cf = chunk >> 4, ks = chunk & 15;
        int col = cf * 16 + (l & 15);
        int kb  = ks * 32 + (l >> 4) * 8;
        union { bf16 e[8]; uint4 u; } pk;
#pragma unroll
        for (int ei = 0; ei < 8; ++ei)
            pk.e[ei] = cvt(Wqkv[(size_t)(kb + ei) * C3 + col]);
        *reinterpret_cast<uint4*>(Wq_frag + (size_t)chunk * 512 + l * 8) = pk.u;
    } else {
        int j = (b - 384) * 256 + t;   // 0..262143
        int k = j >> 9, c = j & 511;
        Wp_t[(size_t)c * CDIM + k] = cvt(Wproj[(size_t)k * CDIM + c]);
    }
}

// k_gather: feat -> fragment-native gathered A:  chunk(rf,ks) from rows
// order[rf*16 + (l&15)].  Writes are perfectly coalesced 1KB chunks.
__global__ __launch_bounds__(256) void k_gather(
    const float* __restrict__ feat, const int* __restrict__ order,
    bf16* __restrict__ Afrag)
{
    const int rf = blockIdx.x;           // 0..8191
    const int t = threadIdx.x, wv = t >> 6, l = t & 63;
    const int srow = order[rf * 16 + (l & 15)];
    const float* src = feat + (size_t)srow * CDIM + (l >> 4) * 8;
#pragma unroll
    for (int q = 0; q < 4; ++q) {
        int ks = wv * 4 + q;
        float4 v0 = *reinterpret_cast<const float4*>(src + ks * 32);
        float4 v1 = *reinterpret_cast<const float4*>(src + ks * 32 + 4);
        union { bf16 e[8]; uint4 u; } pk;
        pk.e[0] = cvt(v0.x); pk.e[1] = cvt(v0.y);
        pk.e[2] = cvt(v0.z); pk.e[3] = cvt(v0.w);
        pk.e[4] = cvt(v1.x); pk.e[5] = cvt(v1.y);
        pk.e[6] = cvt(v1.z); pk.e[7] = cvt(v1.w);
        *reinterpret_cast<uint4*>(
            Afrag + ((size_t)rf * 16 + ks) * 512 + l * 8) = pk.u;
    }
}

// ---------------------------------------------------------------------------
// qkv GEMM — ZERO LDS, ZERO barriers. Both operands fragment-native in global
// (A = gathered feat, L2/HBM; B = Wq_frag, 1.5MB L2-hot). 256x256 tile,
// 8 waves (2M x 4N), wave owns 128x64 (8x4 frags, acc 128 regs). Frag regs
// double-buffered; per k-step: 12 coalesced 1KB loads (next step) + 32 MFMA
// (current step). Compiler inserts counted vmcnt => hardware prefetch pipe.
// ---------------------------------------------------------------------------
template <int NT>
__global__ __launch_bounds__(512, 2) void k_mm_frag(
    const bf16* __restrict__ Afrag, const bf16* __restrict__ Bfrag,
    const float* __restrict__ bias, bf16* __restrict__ outp)
{
    const int t    = threadIdx.x;
    const int lane = t & 63;
    const int wv   = t >> 6;          // 0..7
    const int wr   = wv >> 2;         // 0..1  (M half: 128 rows)
    const int wc   = wv & 3;          // 0..3  (N quarter: 64 cols)
    const int g    = lane >> 4, r16 = lane & 15;

    const int nwg = gridDim.x;
    const int bid = blockIdx.x;
    const int swz = (bid & 7) * (nwg >> 3) + (bid >> 3);  // grids %8==0
    const int m0  = (swz / NT) * 256;
    const int n0  = (swz % NT) * 256;

    // frag-chunk bases: m-frag i at +i*8192 el, k-step at +ks*512 el.
    const bf16* pA = Afrag + (size_t)(m0 / 16 + wr * 8) * 8192 + lane * 8;
    const bf16* pB = Bfrag + (size_t)(n0 / 16 + wc * 4) * 8192 + lane * 8;

    f32x4 acc[8][4];
    const f32x4 z = {0.f, 0.f, 0.f, 0.f};
#pragma unroll
    for (int i = 0; i < 8; ++i)
#pragma unroll
        for (int n = 0; n < 4; ++n) acc[i][n] = z;

    bf16x8 aR[2][8], bR[2][4];        // static idx under full unroll

    auto LD = [&](int set, int ks) {
#pragma unroll
        for (int i = 0; i < 8; ++i)
            aR[set][i] = *reinterpret_cast<const bf16x8*>(pA + i * 8192 + ks * 512);
#pragma unroll
        for (int n = 0; n < 4; ++n)
            bR[set][n] = *reinterpret_cast<const bf16x8*>(pB + n * 8192 + ks * 512);
    };

    LD(0, 0);
#pragma unroll
    for (int ks = 0; ks < NKS; ++ks) {
        if (ks + 1 < NKS) LD((ks + 1) & 1, ks + 1);
        __builtin_amdgcn_s_setprio(1);
#pragma unroll
        for (int i = 0; i < 8; ++i)
#pragma unroll
            for (int n = 0; n < 4; ++n)
                acc[i][n] = __builtin_amdgcn_mfma_f32_16x16x32_bf16(
                    aR[ks & 1][i], bR[ks & 1][n], acc[i][n], 0, 0, 0);
        __builtin_amdgcn_s_setprio(0);
    }

    // epilogue: D layout col=lane&15, row=(lane>>4)*4+j (verified)
    const int ldo = NT * 256;
#pragma unroll
    for (int n = 0; n < 4; ++n) {
        int col = n0 + wc * 64 + n * 16 + r16;
        float b = bias[col];
#pragma unroll
        for (int i = 0; i < 8; ++i)
#pragma unroll
            for (int j = 0; j < 4; ++j) {
                int row = m0 + wr * 128 + i * 16 + g * 4 + j;
                outp[(size_t)row * ldo + col] = cvt(acc[i][n][j] + b);
            }
    }
}

// ---------------------------------------------------------------------------
// proj GEMM — R5 structure verbatim (proven 2 blocks/CU, conflicts=0):
// 128x256 tile, BK=32, 8 waves, 2-deep ring, rotate-permute LDS, vmcnt(3).
// ---------------------------------------------------------------------------
template <bool F32OUT, int NT>
__global__ __launch_bounds__(512, 4) void k_gemm(
    const bf16* __restrict__ Ag, const bf16* __restrict__ Bt,
    const float* __restrict__ bias, void* __restrict__ outp)
{
    __shared__ __align__(16) bf16 As[2][128 * 32];
    __shared__ __align__(16) bf16 Bs[2][256 * 32];

    const int t    = threadIdx.x;
    const int lane = t & 63;
    const int wv   = t >> 6;
    const int wr   = wv >> 2;
    const int wc   = wv & 3;
    const int g    = lane >> 4, r16 = lane & 15;

    const int nwg = gridDim.x;
    const int bid = blockIdx.x;
    const int swz = (bid & 7) * (nwg >> 3) + (bid >> 3);
    const int m0  = (swz / NT) * 128;
    const int n0  = (swz % NT) * 256;

    const int L0 = wv * 64 + lane;
    const int rA = L0 >> 2,          sA = ((L0 & 3) - (rA >> 1)) & 3;
    const int rB1 = rA + 128,        sB1v = ((L0 & 3) - (rB1 >> 1)) & 3;
    const bf16* srcA  = Ag + (size_t)(m0 + rA) * CDIM + sA * 8;
    const bf16* srcB0 = Bt + (size_t)(n0 + rA) * CDIM + sA * 8;
    const bf16* srcB1 = Bt + (size_t)(n0 + rB1) * CDIM + sB1v * 8;

    int aoff[4], boff[4];
#pragma unroll
    for (int m = 0; m < 4; ++m) {
        int row = wr * 64 + m * 16 + r16;
        aoff[m] = row * 64 + (((g + (row >> 1)) & 3) << 4);
    }
#pragma unroll
    for (int n = 0; n < 4; ++n) {
        int row = wc * 64 + n * 16 + r16;
        boff[n] = row * 64 + (((g + (row >> 1)) & 3) << 4);
    }

    f32x4 acc[4][4];
    const f32x4 z = {0.f, 0.f, 0.f, 0.f};
#pragma unroll
    for (int m = 0; m < 4; ++m)
#pragma unroll
        for (int n = 0; n < 4; ++n) acc[m][n] = z;

    auto stage = [&](int kt) {
        const int b  = kt & 1;
        const int ko = kt * 32;
        gld16(srcA  + ko, &As[b][(size_t)wv * 64 * 8]);
        gld16(srcB0 + ko, &Bs[b][(size_t)wv * 64 * 8]);
        gld16(srcB1 + ko, &Bs[b][(size_t)(512 + wv * 64) * 8]);
    };

    auto compute = [&](int kt) {
        const int b = kt & 1;
        bf16x8 af[4], bvv[4];
#pragma unroll
        for (int m = 0; m < 4; ++m)
            af[m] = *reinterpret_cast<const bf16x8*>(
                reinterpret_cast<const char*>(&As[b][0]) + aoff[m]);
#pragma unroll
        for (int n = 0; n < 4; ++n)
            bvv[n] = *reinterpret_cast<const bf16x8*>(
                reinterpret_cast<const char*>(&Bs[b][0]) + boff[n]);
        __builtin_amdgcn_s_setprio(1);
#pragma unroll
        for (int m = 0; m < 4; ++m)
#pragma unroll
            for (int n = 0; n < 4; ++n)
                acc[m][n] = __builtin_amdgcn_mfma_f32_16x16x32_bf16(
                    af[m], bvv[n], acc[m][n], 0, 0, 0);
        __builtin_amdgcn_s_setprio(0);
    };

    const int NKT = CDIM / 32;

    stage(0); stage(1);
    asm volatile("s_waitcnt vmcnt(3)" ::: "memory");
    __builtin_amdgcn_s_barrier();

#pragma unroll
    for (int kt = 0; kt < NKT - 2; ++kt) {
        compute(kt);
        asm volatile("s_waitcnt lgkmcnt(0)" ::: "memory");
        __builtin_amdgcn_s_barrier();
        stage(kt + 2);
        asm volatile("s_waitcnt vmcnt(3)" ::: "memory");
        __builtin_amdgcn_s_barrier();
    }
    compute(NKT - 2);
    asm volatile("s_waitcnt vmcnt(0) lgkmcnt(0)" ::: "memory");
    __builtin_amdgcn_s_barrier();
    compute(NKT - 1);

    const int ldo = NT * 256;
#pragma unroll
    for (int n = 0; n < 4; ++n) {
        int col = n0 + wc * 64 + n * 16 + r16;
        float b = bias[col];
#pragma unroll
        for (int m = 0; m < 4; ++m)
#pragma unroll
            for (int j = 0; j < 4; ++j) {
                int row = m0 + wr * 64 + m * 16 + g * 4 + j;
                if (F32OUT)
                    reinterpret_cast<float*>(outp)[(size_t)row * ldo + col] =
                        acc[m][n][j] + b;
                else
                    reinterpret_cast<bf16*>(outp)[(size_t)row * ldo + col] =
                        cvt(acc[m][n][j] + b);
            }
    }
}

// ---------------------------------------------------------------------------
// Attention: one block per (window, head). 4 waves, each owns 32 query rows.
// Output rows SCATTERED to attn_g[order[w*128+tok]] (so proj's A is sequential).
// ---------------------------------------------------------------------------
__global__ __launch_bounds__(256) void k_attn(
    const bf16* __restrict__ qkv_s, const int* __restrict__ order,
    bf16* __restrict__ attn_g)
{
    __shared__ __align__(16) char smem[36864 + 64 * 136 * 2];
    __shared__ int ord_s[KWIN];
    bf16 (*Q)[72]   = reinterpret_cast<bf16 (*)[72]>(smem);
    bf16 (*Kt)[72]  = reinterpret_cast<bf16 (*)[72]>(smem + 128 * 72 * 2);
    bf16 (*P)[136]  = reinterpret_cast<bf16 (*)[136]>(smem);
    bf16 (*Vt)[136] = reinterpret_cast<bf16 (*)[136]>(smem + 36864);

    const int t    = threadIdx.x;
    const int lane = t & 63;
    const int wv   = t >> 6;
    const int g    = lane >> 4, r16 = lane & 15;
    const int h    = blockIdx.x;
    const int w    = blockIdx.y;

    const bf16* base = qkv_s + (size_t)w * KWIN * C3 + h * HD;

    if (t < KWIN) ord_s[t] = order[w * KWIN + t];

#pragma unroll
    for (int it = 0; it < 4; ++it) {
        int s   = it * 256 + t;
        int tok = s >> 3;
        int c8  = (s & 7) << 3;
        size_t roff = (size_t)tok * C3 + c8;
        *reinterpret_cast<uint4*>(&Q[tok][c8])  =
            *reinterpret_cast<const uint4*>(base + roff);
        *reinterpret_cast<uint4*>(&Kt[tok][c8]) =
            *reinterpret_cast<const uint4*>(base + roff + CDIM);
        uint4 vvec = *reinterpret_cast<const uint4*>(base + roff + 2 * CDIM);
        const bf16* ve = reinterpret_cast<const bf16*>(&vvec);
#pragma unroll
        for (int i = 0; i < 8; ++i) Vt[c8 + i][tok] = ve[i];
    }
    __syncthreads();

    f32x4 sc[2][8];
    const f32x4 z = {0.f, 0.f, 0.f, 0.f};
#pragma unroll
    for (int m = 0; m < 2; ++m)
#pragma unroll
        for (int n = 0; n < 8; ++n) sc[m][n] = z;

#pragma unroll
    for (int ks = 0; ks < 2; ++ks) {
        bf16x8 aq[2];
#pragma unroll
        for (int m = 0; m < 2; ++m)
            aq[m] = *reinterpret_cast<const bf16x8*>(
                &Q[wv * 32 + m * 16 + r16][ks * 32 + g * 8]);
#pragma unroll
        for (int n = 0; n < 8; ++n) {
            bf16x8 bk = *reinterpret_cast<const bf16x8*>(
                &Kt[n * 16 + r16][ks * 32 + g * 8]);
#pragma unroll
            for (int m = 0; m < 2; ++m)
                sc[m][n] = __builtin_amdgcn_mfma_f32_16x16x32_bf16(
                    aq[m], bk, sc[m][n], 0, 0, 0);
        }
    }

    const float scale = 0.125f;
    float inv_sum[2][4];
#pragma unroll
    for (int m = 0; m < 2; ++m) {
#pragma unroll
        for (int j = 0; j < 4; ++j) {
            float mx = -3.0e38f;
#pragma unroll
            for (int n = 0; n < 8; ++n) mx = fmaxf(mx, sc[m][n][j]);
            mx = fmaxf(mx, __shfl_xor(mx, 1));
            mx = fmaxf(mx, __shfl_xor(mx, 2));
            mx = fmaxf(mx, __shfl_xor(mx, 4));
            mx = fmaxf(mx, __shfl_xor(mx, 8));
            mx *= scale;
            float ssum = 0.f;
#pragma unroll
            for (int n = 0; n < 8; ++n) {
                float p = __expf(sc[m][n][j] * scale - mx);
                sc[m][n][j] = p;
                ssum += p;
            }
            ssum += __shfl_xor(ssum, 1);
            ssum += __shfl_xor(ssum, 2);
            ssum += __shfl_xor(ssum, 4);
            ssum += __shfl_xor(ssum, 8);
            inv_sum[m][j] = 1.f / ssum;
        }
    }

    __syncthreads();

#pragma unroll
    for (int m = 0; m < 2; ++m)
#pragma unroll
        for (int n = 0; n < 8; ++n)
#pragma unroll
            for (int j = 0; j < 4; ++j)
                P[wv * 32 + m * 16 + g * 4 + j][n * 16 + r16] =
                    cvt(sc[m][n][j] * inv_sum[m][j]);

    f32x4 o[2][4];
#pragma unroll
    for (int m = 0; m < 2; ++m)
#pragma unroll
        for (int n = 0; n < 4; ++n) o[m][n] = z;

#pragma unroll
    for (int kt = 0; kt < 4; ++kt) {
        bf16x8 ap[2];
#pragma unroll
        for (int m = 0; m < 2; ++m)
            ap[m] = *reinterpret_cast<const bf16x8*>(
                &P[wv * 32 + m * 16 + r16][kt * 32 + g * 8]);
#pragma unroll
        for (int n = 0; n < 4; ++n) {
            bf16x8 bvv = *reinterpret_cast<const bf16x8*>(
                &Vt[n * 16 + r16][kt * 32 + g * 8]);
#pragma unroll
            for (int m = 0; m < 2; ++m)
                o[m][n] = __builtin_amdgcn_mfma_f32_16x16x32_bf16(
                    ap[m], bvv, o[m][n], 0, 0, 0);
        }
    }

#pragma unroll
    for (int m = 0; m < 2; ++m)
#pragma unroll
        for (int n = 0; n < 4; ++n)
#pragma unroll
            for (int j = 0; j < 4; ++j) {
                int tok  = wv * 32 + m * 16 + g * 4 + j;
                int d    = n * 16 + r16;
                int drow = ord_s[tok];
                attn_g[(size_t)drow * CDIM + h * HD + d] = cvt(o[m][n][j]);
            }
}

// ---------------------------------------------------------------------------
extern "C" void kernel_launch(void* const* d_in, const int* in_sizes, int n_in,
                              void* d_out, int out_size, void* d_ws, size_t ws_size,
                              hipStream_t stream)
{
    const float* feat    = (const float*)d_in[0];
    const float* Wqkv    = (const float*)d_in[1];
    const float* bqkv    = (const float*)d_in[2];
    const float* Wproj   = (const float*)d_in[3];
    const float* bproj   = (const float*)d_in[4];
    const int*   order   = (const int*)d_in[5];
    float* out = (float*)d_out;

    const size_t qkv_bytes = (size_t)N_PTS * C3 * sizeof(bf16);    // 402.7 MB
    const size_t gat_bytes = (size_t)N_PTS * CDIM * sizeof(bf16);  // 134.2 MB
    const size_t wq_bytes  = (size_t)C3 * CDIM * sizeof(bf16);
    const size_t wp_bytes  = (size_t)CDIM * CDIM * sizeof(bf16);
    if (ws_size < qkv_bytes + gat_bytes + wq_bytes + wp_bytes) return;

    bf16* qkv_s     = (bf16*)d_ws;
    bf16* shared134 = (bf16*)((char*)d_ws + qkv_bytes);   // Afrag, later attn_g
    bf16* Wq_frag   = (bf16*)((char*)d_ws + qkv_bytes + gat_bytes);
    bf16* Wp_t      = (bf16*)((char*)d_ws + qkv_bytes + gat_bytes + wq_bytes);

    // prep: 384 blocks for Wq_frag (1536 chunks), 1024 for Wp_t
    k_prep<<<dim3(384 + 1024), 256, 0, stream>>>(Wqkv, Wproj, Wq_frag, Wp_t);
    // gather into fragment-native A (8192 rowfrags)
    k_gather<<<dim3(N_PTS / 16), 256, 0, stream>>>(feat, order, shared134);
    // qkv GEMM, no LDS: (131072/256)x(1536/256) = 3072 blocks
    k_mm_frag<C3 / 256><<<dim3((N_PTS / 256) * (C3 / 256)), 512, 0, stream>>>(
        shared134, Wq_frag, bqkv, qkv_s);
    // attention (reads qkv_s, scatters into shared134 = attn_g)
    k_attn<<<dim3(NH, N_PTS / KWIN), 256, 0, stream>>>(qkv_s, order, shared134);
    // proj GEMM (R5 path): (131072/128)x(512/256) = 2048 blocks
    k_gemm<true, CDIM / 256><<<dim3((N_PTS / 128) * (CDIM / 256)), 512, 0, stream>>>(
        shared134, Wp_t, bproj, out);
}

// Round 11
// 626.933 us; speedup vs baseline: 1.4077x; 1.4077x over previous
//
#include <hip/hip_runtime.h>
#include <hip/hip_bf16.h>
#include <cstdint>
#include <cstddef>

typedef __bf16 bf16;
typedef __bf16 bf16x8 __attribute__((ext_vector_type(8)));
typedef float f32x4 __attribute__((ext_vector_type(4)));

#define N_PTS 131072
#define CDIM  512
#define C3    1536
#define HD    64
#define NH    8
#define KWIN  128

static __device__ __forceinline__ bf16 cvt(float x) { return (bf16)x; }

// async global->LDS, 16B per lane. LDS dest = wave-uniform base + lane*16.
static __device__ __forceinline__ void gld16(const bf16* g, bf16* l) {
    __builtin_amdgcn_global_load_lds(
        (const __attribute__((address_space(1))) void*)g,
        (__attribute__((address_space(3))) void*)l, 16, 0, 0);
}

// ---------------------------------------------------------------------------
// Weight prep: transpose + cast f32 -> bf16.  Wt[col][k] = W[k][col].
// ---------------------------------------------------------------------------
__global__ __launch_bounds__(256) void k_prep(
    const float* __restrict__ Wqkv, const float* __restrict__ Wproj,
    bf16* __restrict__ Wqkv_t, bf16* __restrict__ Wproj_t)
{
    int idx = blockIdx.x * 256 + threadIdx.x;
    if (idx < CDIM * C3) {
        int k = idx / C3, c = idx % C3;
        Wqkv_t[(size_t)c * CDIM + k] = cvt(Wqkv[idx]);
    } else {
        int j = idx - CDIM * C3;
        if (j < CDIM * CDIM) {
            int k = j / CDIM, c = j % CDIM;
            Wproj_t[(size_t)c * CDIM + k] = cvt(Wproj[j]);
        }
    }
}

// ---------------------------------------------------------------------------
// Gather + cast: feat_g[i][:] = bf16(feat[order[i]][:])
// ---------------------------------------------------------------------------
__global__ __launch_bounds__(256) void k_gather(
    const float* __restrict__ feat, const int* __restrict__ order,
    bf16* __restrict__ feat_g)
{
    int row = blockIdx.x * 2 + (threadIdx.x >> 7);
    int c   = (threadIdx.x & 127) << 2;
    int src = order[row];
    float4 v = *reinterpret_cast<const float4*>(feat + (size_t)src * CDIM + c);
    union { bf16 e[4]; uint2 u; } pk;
    pk.e[0] = cvt(v.x); pk.e[1] = cvt(v.y); pk.e[2] = cvt(v.z); pk.e[3] = cvt(v.w);
    *reinterpret_cast<uint2*>(feat_g + (size_t)row * CDIM + c) = pk.u;
}

// ---------------------------------------------------------------------------
// 8-phase GEMM (faithful m201-style port):  out = A @ Bt^T + bias
// BM=BN=256, BK=64, 8 waves (2M x 4N), wave owns 128x64 (8x4 frags, 128 acc).
// LDS: 2 buffers x (A 32KB + B 32KB) = 128KB, 1 block/CU.
//
// Per K-tile tau (buffer b=tau&1), 4 phases; phase p computes m-group (p&1),
// k-half (p>>1) = 16 MFMA, and ds_reads the NEXT phase's frags (A:4, B:4 on
// p=1,3). Stages: p2 -> B[tau+2] (4 gld16), p3 -> A[tau+2] (4 gld16).
// ONE vmcnt per tile, at p2-end: outstanding = B[t+1](4)+A[t+1](4)+B[t+2](4)
// -> vmcnt(4) retires all of [tau+1], keeps B[tau+2]. Never 0 mid-loop.
// A gets 3-phase HBM cover; B (L2-hot weights) 2-phase.
// WAR: B[tau] reads complete at p1's lgkm0-before-barrier -> p2 stage safe;
//      A[tau] reads complete at p2's lgkm0 -> p3 stage safe.
// Phase template: stage | ds_read(next) | setprio1 16xMFMA setprio0 |
//                 lgkm0 + sched_barrier | [vmcnt] | s_barrier.
//
// LDS swizzle: row stride 128B, 8x16B slots/row; slot(kh,g,row) =
// (kh*4+g+(row&7))&7. Frag reads: row*128B == 0 mod 32 banks -> bank set by
// slot only -> 8 distinct x 2-way = conflict-free. Staging pre-swizzles the
// per-lane GLOBAL source; LDS dest stays linear for gld16.
// ---------------------------------------------------------------------------
template <bool F32OUT, int NT>
__global__ __launch_bounds__(512) void k_gemm8(
    const bf16* __restrict__ Ag, const bf16* __restrict__ Bt,
    const float* __restrict__ bias, void* __restrict__ outp)
{
    __shared__ __align__(16) bf16 As[2][256 * 64];   // 64 KB
    __shared__ __align__(16) bf16 Bs[2][256 * 64];   // 64 KB

    const int t    = threadIdx.x;
    const int lane = t & 63;
    const int wv   = t >> 6;          // 0..7
    const int wr   = wv >> 2;         // 0..1  (M half: 128 rows)
    const int wc   = wv & 3;          // 0..3  (N quarter: 64 cols)
    const int g    = lane >> 4, r16 = lane & 15;

    const int nwg = gridDim.x;
    const int bid = blockIdx.x;
    const int swz = (bid & 7) * (nwg >> 3) + (bid >> 3);  // grids are %8==0
    const int m0  = (swz / NT) * 256;
    const int n0  = (swz % NT) * 256;

    const int NKT = CDIM / 64;   // 8 K-tiles

    // ---- staging maps: (h,j) -> per-lane chunk L = wv*128 + j*64 + lane ----
    // row_l = L>>3 (0..127), phys slot p8 = L&7, src slot s8 = (p8-row_l)&7.
    int aSrc[2][2], bSrc[2][2];    // 32-bit element offsets into Ag / Bt
    int dstE[2][2];                // wave-uniform LDS elem offset (lane auto)
#pragma unroll
    for (int h = 0; h < 2; ++h)
#pragma unroll
        for (int j = 0; j < 2; ++j) {
            int L = wv * 128 + j * 64 + lane;
            int row_l = L >> 3, p8 = L & 7;
            int s8 = (p8 - (row_l & 7)) & 7;
            int grow = h * 128 + row_l;
            aSrc[h][j] = (m0 + grow) * CDIM + s8 * 8;
            bSrc[h][j] = (n0 + grow) * CDIM + s8 * 8;
            dstE[h][j] = h * 8192 + (wv * 128 + j * 64) * 8;
        }

    // ---- frag read byte-offsets ----
    int aoff[2][2][4];   // [grp][kh][q]
    int boff[2][4];      // [kh][n]
#pragma unroll
    for (int grp = 0; grp < 2; ++grp)
#pragma unroll
        for (int kh = 0; kh < 2; ++kh)
#pragma unroll
            for (int q = 0; q < 4; ++q) {
                int row = wr * 128 + (grp * 4 + q) * 16 + r16;
                aoff[grp][kh][q] = row * 128 +
                    (((kh * 4 + g + (r16 & 7)) & 7) << 4);
            }
#pragma unroll
    for (int kh = 0; kh < 2; ++kh)
#pragma unroll
        for (int n = 0; n < 4; ++n) {
            int row = wc * 64 + n * 16 + r16;
            boff[kh][n] = row * 128 +
                (((kh * 4 + g + (r16 & 7)) & 7) << 4);
        }

    f32x4 acc[8][4];
    const f32x4 z = {0.f, 0.f, 0.f, 0.f};
#pragma unroll
    for (int i = 0; i < 8; ++i)
#pragma unroll
        for (int n = 0; n < 4; ++n) acc[i][n] = z;

    bf16x8 afr[2][4], bfr[2][4];

    auto stageA = [&](int tau) {
        const int b = tau & 1, ko = tau * 64;
#pragma unroll
        for (int h = 0; h < 2; ++h)
#pragma unroll
            for (int j = 0; j < 2; ++j)
                gld16(Ag + aSrc[h][j] + ko, &As[b][dstE[h][j]]);
    };
    auto stageB = [&](int tau) {
        const int b = tau & 1, ko = tau * 64;
#pragma unroll
        for (int h = 0; h < 2; ++h)
#pragma unroll
            for (int j = 0; j < 2; ++j)
                gld16(Bt + bSrc[h][j] + ko, &Bs[b][dstE[h][j]]);
    };
    auto readA = [&](int set, int b, int grp, int kh) {
        const char* ab = reinterpret_cast<const char*>(&As[b][0]);
#pragma unroll
        for (int q = 0; q < 4; ++q)
            afr[set][q] = *reinterpret_cast<const bf16x8*>(ab + aoff[grp][kh][q]);
    };
    auto readB = [&](int b, int kh) {
        const char* bb = reinterpret_cast<const char*>(&Bs[b][0]);
#pragma unroll
        for (int n = 0; n < 4; ++n)
            bfr[kh][n] = *reinterpret_cast<const bf16x8*>(bb + boff[kh][n]);
    };

    // ---------------- prologue ----------------
    stageB(0); stageA(0); stageB(1); stageA(1);          // 16 loads
    asm volatile("s_waitcnt vmcnt(8)" ::: "memory");      // tile 0 resident
    __builtin_amdgcn_s_barrier();
    readA(0, 0, 0, 0);                                    // frags for pi=0
    readB(0, 0);
    asm volatile("s_waitcnt lgkmcnt(0)" ::: "memory");
    __builtin_amdgcn_sched_barrier(0);

    // ---------------- main loop: 8 tiles x 4 phases ----------------
#pragma unroll
    for (int tau = 0; tau < NKT; ++tau) {
#pragma unroll
        for (int p = 0; p < 4; ++p) {
            const int pi  = tau * 4 + p;
            const int grp = p & 1, kh = p >> 1;

            // stages (issue first = oldest)
            if (p == 2 && tau + 2 < NKT) stageB(tau + 2);
            if (p == 3 && tau + 2 < NKT) stageA(tau + 2);

            // ds_read next phase's frags
            if (pi + 1 < NKT * 4) {
                const int pn   = (p + 1) & 3;
                const int taun = tau + (p == 3);
                const int bn   = taun & 1;
                readA((pi + 1) & 1, bn, pn & 1, pn >> 1);
                if (pn == 0 || pn == 2) readB(bn, pn >> 1);
            }

            // MFMA current phase
            __builtin_amdgcn_s_setprio(1);
#pragma unroll
            for (int q = 0; q < 4; ++q)
#pragma unroll
                for (int n = 0; n < 4; ++n)
                    acc[grp * 4 + q][n] = __builtin_amdgcn_mfma_f32_16x16x32_bf16(
                        afr[pi & 1][q], bfr[kh][n], acc[grp * 4 + q][n], 0, 0, 0);
            __builtin_amdgcn_s_setprio(0);

            asm volatile("s_waitcnt lgkmcnt(0)" ::: "memory");
            __builtin_amdgcn_sched_barrier(0);
            if (p == 2) {
                if (tau + 2 < NKT)
                    asm volatile("s_waitcnt vmcnt(4)" ::: "memory");
                else
                    asm volatile("s_waitcnt vmcnt(0)" ::: "memory");
            }
            __builtin_amdgcn_s_barrier();
        }
    }

    // ---------------- epilogue: D layout col=lane&15, row=(lane>>4)*4+j ----
    const int ldo = NT * 256;
#pragma unroll
    for (int n = 0; n < 4; ++n) {
        int col = n0 + wc * 64 + n * 16 + r16;
        float b = bias[col];
#pragma unroll
        for (int i = 0; i < 8; ++i)
#pragma unroll
            for (int j = 0; j < 4; ++j) {
                int row = m0 + wr * 128 + i * 16 + g * 4 + j;
                if (F32OUT)
                    reinterpret_cast<float*>(outp)[(size_t)row * ldo + col] =
                        acc[i][n][j] + b;
                else
                    reinterpret_cast<bf16*>(outp)[(size_t)row * ldo + col] =
                        cvt(acc[i][n][j] + b);
            }
    }
}

// ---------------------------------------------------------------------------
// Attention: one block per (window, head). 4 waves, each owns 32 query rows.
// Output rows SCATTERED to attn_g[order[w*128+tok]] (so proj's A is sequential).
// ---------------------------------------------------------------------------
__global__ __launch_bounds__(256) void k_attn(
    const bf16* __restrict__ qkv_s, const int* __restrict__ order,
    bf16* __restrict__ attn_g)
{
    __shared__ __align__(16) char smem[36864 + 64 * 136 * 2];
    __shared__ int ord_s[KWIN];
    bf16 (*Q)[72]   = reinterpret_cast<bf16 (*)[72]>(smem);
    bf16 (*Kt)[72]  = reinterpret_cast<bf16 (*)[72]>(smem + 128 * 72 * 2);
    bf16 (*P)[136]  = reinterpret_cast<bf16 (*)[136]>(smem);
    bf16 (*Vt)[136] = reinterpret_cast<bf16 (*)[136]>(smem + 36864);

    const int t    = threadIdx.x;
    const int lane = t & 63;
    const int wv   = t >> 6;
    const int g    = lane >> 4, r16 = lane & 15;
    const int h    = blockIdx.x;
    const int w    = blockIdx.y;

    const bf16* base = qkv_s + (size_t)w * KWIN * C3 + h * HD;

    if (t < KWIN) ord_s[t] = order[w * KWIN + t];

#pragma unroll
    for (int it = 0; it < 4; ++it) {
        int s   = it * 256 + t;
        int tok = s >> 3;
        int c8  = (s & 7) << 3;
        size_t roff = (size_t)tok * C3 + c8;
        *reinterpret_cast<uint4*>(&Q[tok][c8])  =
            *reinterpret_cast<const uint4*>(base + roff);
        *reinterpret_cast<uint4*>(&Kt[tok][c8]) =
            *reinterpret_cast<const uint4*>(base + roff + CDIM);
        uint4 vvec = *reinterpret_cast<const uint4*>(base + roff + 2 * CDIM);
        const bf16* ve = reinterpret_cast<const bf16*>(&vvec);
#pragma unroll
        for (int i = 0; i < 8; ++i) Vt[c8 + i][tok] = ve[i];
    }
    __syncthreads();

    f32x4 sc[2][8];
    const f32x4 z = {0.f, 0.f, 0.f, 0.f};
#pragma unroll
    for (int m = 0; m < 2; ++m)
#pragma unroll
        for (int n = 0; n < 8; ++n) sc[m][n] = z;

#pragma unroll
    for (int ks = 0; ks < 2; ++ks) {
        bf16x8 aq[2];
#pragma unroll
        for (int m = 0; m < 2; ++m)
            aq[m] = *reinterpret_cast<const bf16x8*>(
                &Q[wv * 32 + m * 16 + r16][ks * 32 + g * 8]);
#pragma unroll
        for (int n = 0; n < 8; ++n) {
            bf16x8 bk = *reinterpret_cast<const bf16x8*>(
                &Kt[n * 16 + r16][ks * 32 + g * 8]);
#pragma unroll
            for (int m = 0; m < 2; ++m)
                sc[m][n] = __builtin_amdgcn_mfma_f32_16x16x32_bf16(
                    aq[m], bk, sc[m][n], 0, 0, 0);
        }
    }

    const float scale = 0.125f;
    float inv_sum[2][4];
#pragma unroll
    for (int m = 0; m < 2; ++m) {
#pragma unroll
        for (int j = 0; j < 4; ++j) {
            float mx = -3.0e38f;
#pragma unroll
            for (int n = 0; n < 8; ++n) mx = fmaxf(mx, sc[m][n][j]);
            mx = fmaxf(mx, __shfl_xor(mx, 1));
            mx = fmaxf(mx, __shfl_xor(mx, 2));
            mx = fmaxf(mx, __shfl_xor(mx, 4));
            mx = fmaxf(mx, __shfl_xor(mx, 8));
            mx *= scale;
            float ssum = 0.f;
#pragma unroll
            for (int n = 0; n < 8; ++n) {
                float p = __expf(sc[m][n][j] * scale - mx);
                sc[m][n][j] = p;
                ssum += p;
            }
            ssum += __shfl_xor(ssum, 1);
            ssum += __shfl_xor(ssum, 2);
            ssum += __shfl_xor(ssum, 4);
            ssum += __shfl_xor(ssum, 8);
            inv_sum[m][j] = 1.f / ssum;
        }
    }

    __syncthreads();

#pragma unroll
    for (int m = 0; m < 2; ++m)
#pragma unroll
        for (int n = 0; n < 8; ++n)
#pragma unroll
            for (int j = 0; j < 4; ++j)
                P[wv * 32 + m * 16 + g * 4 + j][n * 16 + r16] =
                    cvt(sc[m][n][j] * inv_sum[m][j]);

    f32x4 o[2][4];
#pragma unroll
    for (int m = 0; m < 2; ++m)
#pragma unroll
        for (int n = 0; n < 4; ++n) o[m][n] = z;

#pragma unroll
    for (int kt = 0; kt < 4; ++kt) {
        bf16x8 ap[2];
#pragma unroll
        for (int m = 0; m < 2; ++m)
            ap[m] = *reinterpret_cast<const bf16x8*>(
                &P[wv * 32 + m * 16 + r16][kt * 32 + g * 8]);
#pragma unroll
        for (int n = 0; n < 4; ++n) {
            bf16x8 bvv = *reinterpret_cast<const bf16x8*>(
                &Vt[n * 16 + r16][kt * 32 + g * 8]);
#pragma unroll
            for (int m = 0; m < 2; ++m)
                o[m][n] = __builtin_amdgcn_mfma_f32_16x16x32_bf16(
                    ap[m], bvv, o[m][n], 0, 0, 0);
        }
    }

#pragma unroll
    for (int m = 0; m < 2; ++m)
#pragma unroll
        for (int n = 0; n < 4; ++n)
#pragma unroll
            for (int j = 0; j < 4; ++j) {
                int tok  = wv * 32 + m * 16 + g * 4 + j;
                int d    = n * 16 + r16;
                int drow = ord_s[tok];
                attn_g[(size_t)drow * CDIM + h * HD + d] = cvt(o[m][n][j]);
            }
}

// ---------------------------------------------------------------------------
extern "C" void kernel_launch(void* const* d_in, const int* in_sizes, int n_in,
                              void* d_out, int out_size, void* d_ws, size_t ws_size,
                              hipStream_t stream)
{
    const float* feat    = (const float*)d_in[0];
    const float* Wqkv    = (const float*)d_in[1];
    const float* bqkv    = (const float*)d_in[2];
    const float* Wproj   = (const float*)d_in[3];
    const float* bproj   = (const float*)d_in[4];
    const int*   order   = (const int*)d_in[5];
    float* out = (float*)d_out;

    const size_t qkv_bytes = (size_t)N_PTS * C3 * sizeof(bf16);    // 402.7 MB
    const size_t gat_bytes = (size_t)N_PTS * CDIM * sizeof(bf16);  // 134.2 MB
    const size_t wq_bytes  = (size_t)C3 * CDIM * sizeof(bf16);
    const size_t wp_bytes  = (size_t)CDIM * CDIM * sizeof(bf16);
    if (ws_size < qkv_bytes + gat_bytes + wq_bytes + wp_bytes) return;

    bf16* qkv_s     = (bf16*)d_ws;
    bf16* shared134 = (bf16*)((char*)d_ws + qkv_bytes);   // feat_g, later attn_g
    bf16* Wqkv_t    = (bf16*)((char*)d_ws + qkv_bytes + gat_bytes);
    bf16* Wproj_t   = (bf16*)((char*)d_ws + qkv_bytes + gat_bytes + wq_bytes);

    k_prep<<<dim3((CDIM * C3 + CDIM * CDIM + 255) / 256), 256, 0, stream>>>(
        Wqkv, Wproj, Wqkv_t, Wproj_t);
    k_gather<<<dim3(N_PTS / 2), 256, 0, stream>>>(feat, order, shared134);
    // qkv GEMM: [131072 x 1536] = feat_g @ Wqkv_t^T  (512 x 6 = 3072 blocks)
    k_gemm8<false, C3 / 256><<<dim3((N_PTS / 256) * (C3 / 256)), 512, 0, stream>>>(
        shared134, Wqkv_t, bqkv, qkv_s);
    // attention (reads qkv_s, scatters into shared134 = attn_g)
    k_attn<<<dim3(NH, N_PTS / KWIN), 256, 0, stream>>>(qkv_s, order, shared134);
    // proj GEMM: [131072 x 512] = attn_g @ Wproj_t^T  (512 x 2 = 1024 blocks)
    k_gemm8<true, CDIM / 256><<<dim3((N_PTS / 256) * (CDIM / 256)), 512, 0, stream>>>(
        shared134, Wproj_t, bproj, out);
}